// Round 14
// baseline (356.732 us; speedup 1.0000x reference)
//
#include <hip/hip_runtime.h>
#include <cstdint>

typedef unsigned short u16;
typedef __attribute__((ext_vector_type(8))) short s16x8;   // 8 bf16 (4 VGPR) MFMA A/B frag
typedef __attribute__((ext_vector_type(4))) unsigned short u16x4;
typedef __attribute__((ext_vector_type(4))) float f32x4;   // MFMA C/D frag

// ---------- helpers ----------
__device__ __forceinline__ u16 f2bf(float f) {
  union { float f; uint32_t u; } c; c.f = f;
  uint32_t r = c.u + 0x7FFFu + ((c.u >> 16) & 1u);   // RNE
  return (u16)(r >> 16);
}
__device__ __forceinline__ float bf2f(u16 b) {
  union { uint32_t u; float f; } c; c.u = ((uint32_t)b) << 16;
  return c.f;
}
__device__ __forceinline__ float wave_sum_f(float v) {
#pragma unroll
  for (int o = 32; o > 0; o >>= 1) v += __shfl_xor(v, o);
  return v;
}
__device__ __forceinline__ float wave_max_f(float v) {
#pragma unroll
  for (int o = 32; o > 0; o >>= 1) v = fmaxf(v, __shfl_xor(v, o));
  return v;
}
// async global->LDS, 16B per lane, wave-uniform LDS base (+lane*16 implicit)
__device__ __forceinline__ void gload16(const u16* g, u16* l) {
  __builtin_amdgcn_global_load_lds(
      (const __attribute__((address_space(1))) unsigned int*)g,
      (__attribute__((address_space(3))) unsigned int*)l,
      16, 0, 0);
}

// ---------- elementwise cast fp32 -> bf16 ----------
__global__ __launch_bounds__(256)
void cast_f32_bf16(const float* __restrict__ in, u16* __restrict__ out) {
  long i = ((long)blockIdx.x * 256 + threadIdx.x) * 4;
  f32x4 v = *(const f32x4*)(in + i);
  u16x4 o;
#pragma unroll
  for (int j = 0; j < 4; ++j) o[j] = f2bf(v[j]);
  *(u16x4*)(out + i) = o;
}

// ---------- concat 3 bias vectors (1024 each) ----------
__global__ __launch_bounds__(256)
void concat3(const float* __restrict__ a, const float* __restrict__ b,
             const float* __restrict__ c, float* __restrict__ o) {
  int i = blockIdx.x * 256 + threadIdx.x;
  o[i] = i < 1024 ? a[i] : (i < 2048 ? b[i - 1024] : c[i - 2048]);
}

// ---------- cast+transpose fp32 [R][C] -> bf16 [C][R] ----------
__global__ __launch_bounds__(256)
void transpose_cast_f32_bf16(const float* __restrict__ in, u16* __restrict__ out,
                             int R, int C) {
  __shared__ float tile[32][33];
  int r0 = blockIdx.y * 32, c0 = blockIdx.x * 32;
  int tid = threadIdx.x;
  int tr = tid >> 3, tc4 = (tid & 7) * 4;
  f32x4 v = *(const f32x4*)(in + (long)(r0 + tr) * C + c0 + tc4);
#pragma unroll
  for (int j = 0; j < 4; ++j) tile[tr][tc4 + j] = v[j];
  __syncthreads();
  u16x4 o;
#pragma unroll
  for (int j = 0; j < 4; ++j) o[j] = f2bf(tile[tc4 + j][tr]);
  *(u16x4*)(out + (long)(c0 + tr) * R + r0 + tc4) = o;
}

// ---------- strided transpose bf16: in[z][r][c] (row stride in_rs) -> out[z][c][r] ----------
__global__ __launch_bounds__(256)
void transpose_bf16(const u16* __restrict__ in, u16* __restrict__ out,
                    int R, int C, int in_rs, long in_batch, long out_batch) {
  __shared__ u16 tile[32][36];
  const long zin = (long)blockIdx.z * in_batch;
  const long zout = (long)blockIdx.z * out_batch;
  int r0 = blockIdx.y * 32, c0 = blockIdx.x * 32;
  int tid = threadIdx.x;
  int tr = tid >> 3, tc4 = (tid & 7) * 4;
  u16x4 v = *(const u16x4*)(in + zin + (long)(r0 + tr) * in_rs + c0 + tc4);
#pragma unroll
  for (int j = 0; j < 4; ++j) tile[tr][tc4 + j] = v[j];
  __syncthreads();
  u16x4 o;
#pragma unroll
  for (int j = 0; j < 4; ++j) o[j] = tile[tc4 + j][tr];
  *(u16x4*)(out + zout + (long)(c0 + tr) * R + r0 + tc4) = o;
}

#define TBM 256
#define TBK 64

enum { EPI_BF16_BIAS = 0, EPI_BF16_SCALE = 1, EPI_BF16 = 2,
       EPI_RELU_BF16_BIAS = 3, EPI_BF16_BIAS_RESIDBF = 4 };

#define QUAD(MFA)                                                             \
  _Pragma("unroll")                                                           \
  for (int mf = (MFA); mf < (MFA) + 2; ++mf)                                  \
    _Pragma("unroll")                                                         \
    for (int nf = 0; nf < 4; ++nf) {                                          \
      acc[mf][nf] = __builtin_amdgcn_mfma_f32_16x16x32_bf16(                  \
          af[mf][0], bfr[nf][0], acc[mf][nf], 0, 0, 0);                       \
      acc[mf][nf] = __builtin_amdgcn_mfma_f32_16x16x32_bf16(                  \
          af[mf][1], bfr[nf][1], acc[mf][nf], 0, 0, 0);                       \
    }

__device__ __forceinline__ void epi_store(int EPIv, void* Cout, long cidx,
                                          float v, const float* bias, int col,
                                          const u16* resid, float scale) {
  if (EPIv == EPI_BF16_BIAS) {
    ((u16*)Cout)[cidx] = f2bf(v + bias[col]);
  } else if (EPIv == EPI_BF16_SCALE) {
    ((u16*)Cout)[cidx] = f2bf(v * scale);
  } else if (EPIv == EPI_BF16) {
    ((u16*)Cout)[cidx] = f2bf(v);
  } else if (EPIv == EPI_RELU_BF16_BIAS) {
    ((u16*)Cout)[cidx] = f2bf(fmaxf(v + bias[col], 0.0f));
  } else { // EPI_BF16_BIAS_RESIDBF
    ((u16*)Cout)[cidx] = f2bf(v + bias[col] + bf2f(resid[cidx]));
  }
}

// ---------- 8-wave 256x256 MFMA GEMM (R11-measured best for scores shape) ----------
template <int EPI>
__global__ __launch_bounds__(512, 2)
void gemm8p(const u16* __restrict__ A, const u16* __restrict__ Bt,
            const float* __restrict__ bias, const u16* __restrict__ resid,
            void* __restrict__ Cout, int M, int N, int K, int lda, int ldb,
            int tx, int ty, long long batchA, long long batchB, long long batchC,
            float scale) {
  constexpr int BN_ = 256;
  constexpr int MF = 8;
  __shared__ u16 As[2][TBM * TBK];  // 2 x 32 KB
  __shared__ u16 Bs[2][BN_ * TBK];  // 2 x 32 KB

  // bijective XCD swizzle (m204)
  const int nwg = gridDim.x;
  const int orig = blockIdx.x;
  const int q = nwg >> 3, r = nwg & 7;
  const int xcd = orig & 7, idx = orig >> 3;
  const int wg = (xcd < r ? xcd * (q + 1) : r * (q + 1) + (xcd - r) * q) + idx;
  const int bx = wg % tx;
  const int tmp = wg / tx;
  const int by = tmp % ty;
  const int b  = tmp / ty;

  const u16* Ab = A + (long)b * batchA;
  const u16* Bb = Bt + (long)b * batchB;
  const int row0 = by * TBM;
  const int col0 = bx * BN_;
  const int tid = threadIdx.x;
  const int lane = tid & 63, wid = tid >> 6;     // 8 waves
  const int wm = wid >> 2, wn = wid & 3;         // 2M x 4N
  const int rowW = wm * 128;
  const int l15 = lane & 15, g = lane >> 4;

  const int sr = lane >> 3;
  const int sc = ((lane & 7) ^ sr) * 8;
  const int wrow = wid * 8 + sr;

  const int c0 = ((0 + g) ^ (l15 & 7)) * 8;
  const int c1 = ((4 + g) ^ (l15 & 7)) * 8;

  auto stageA = [&](int h, int kt, int bf_) {
#pragma unroll
    for (int j = 0; j < 2; ++j)
      gload16(Ab + (size_t)(row0 + h * 128 + j * 64 + wrow) * lda + kt * TBK + sc,
              &As[bf_][(h * 128 + j * 64 + wid * 8) * TBK]);
  };
  auto stageB = [&](int h, int kt, int bf_) {
#pragma unroll
    for (int j = 0; j < 2; ++j)
      gload16(Bb + (size_t)(col0 + h * 128 + j * 64 + wrow) * ldb + kt * TBK + sc,
              &Bs[bf_][(h * 128 + j * 64 + wid * 8) * TBK]);
  };

  s16x8 af[MF][2];
  s16x8 bfr[4][2];
  f32x4 acc[MF][4] = {};
  const int nt = K / TBK;

  stageA(0, 0, 0); stageA(1, 0, 0);
  stageB(0, 0, 0); stageB(1, 0, 0);
  if (nt > 1) {
    stageA(0, 1, 1); stageA(1, 1, 1);
    asm volatile("s_waitcnt vmcnt(4)" ::: "memory");
  } else {
    asm volatile("s_waitcnt vmcnt(0)" ::: "memory");
  }
  __builtin_amdgcn_s_barrier();

  for (int t = 0; t < nt; ++t) {
    const int cur = t & 1;
    const u16* Asc = &As[cur][0];
    const u16* Bsc = &Bs[cur][0];

    // ---- phase 0
#pragma unroll
    for (int nf = 0; nf < 4; ++nf) {
      const int rb = (wn * 64 + nf * 16 + l15) * TBK;
      bfr[nf][0] = *(const s16x8*)(Bsc + rb + c0);
      bfr[nf][1] = *(const s16x8*)(Bsc + rb + c1);
    }
#pragma unroll
    for (int mf = 0; mf < 4; ++mf) {
      const int rb = (rowW + mf * 16 + l15) * TBK;
      af[mf][0] = *(const s16x8*)(Asc + rb + c0);
      af[mf][1] = *(const s16x8*)(Asc + rb + c1);
    }
    if (t + 1 < nt) stageB(0, t + 1, cur ^ 1);
    __builtin_amdgcn_s_barrier();
    __builtin_amdgcn_s_setprio(1);
    QUAD(0)
    __builtin_amdgcn_s_setprio(0);
    __builtin_amdgcn_s_barrier();

    // ---- phase 1
#pragma unroll
    for (int mf = 4; mf < 8; ++mf) {
      const int rb = (rowW + mf * 16 + l15) * TBK;
      af[mf][0] = *(const s16x8*)(Asc + rb + c0);
      af[mf][1] = *(const s16x8*)(Asc + rb + c1);
    }
    if (t + 1 < nt) stageB(1, t + 1, cur ^ 1);
    __builtin_amdgcn_s_barrier();
    __builtin_amdgcn_s_setprio(1);
    QUAD(2)
    __builtin_amdgcn_s_setprio(0);
    asm volatile("s_waitcnt lgkmcnt(0)" ::: "memory");
    __builtin_amdgcn_sched_barrier(0);
    __builtin_amdgcn_s_barrier();

    // ---- phase 2
    if (t + 2 < nt) stageA(0, t + 2, cur);
    __builtin_amdgcn_s_barrier();
    __builtin_amdgcn_s_setprio(1);
    QUAD(4)
    __builtin_amdgcn_s_setprio(0);
    __builtin_amdgcn_s_barrier();

    // ---- phase 3
    if (t + 2 < nt) stageA(1, t + 2, cur);
    __builtin_amdgcn_s_barrier();
    __builtin_amdgcn_s_setprio(1);
    QUAD(6)
    __builtin_amdgcn_s_setprio(0);
    if (t + 1 < nt) {
      if (t + 2 < nt) asm volatile("s_waitcnt vmcnt(4)" ::: "memory");
      else            asm volatile("s_waitcnt vmcnt(0)" ::: "memory");
    }
    __builtin_amdgcn_s_barrier();
  }

  const long cb = (long)b * batchC;
#pragma unroll
  for (int mf = 0; mf < MF; ++mf) {
    const int rbase = row0 + rowW + mf * 16 + g * 4;
#pragma unroll
    for (int nf = 0; nf < 4; ++nf) {
      const int col = col0 + wn * 64 + nf * 16 + l15;
#pragma unroll
      for (int rr = 0; rr < 4; ++rr)
        epi_store(EPI, Cout, cb + (long)(rbase + rr) * N + col,
                  acc[mf][nf][rr], bias, col, resid, scale);
    }
  }
}

// ---------- 4-wave 128x128 MFMA GEMM: 2 blocks/CU, 2-phase counted-vmcnt ----------
template <int EPI>
__global__ __launch_bounds__(256, 2)
void gemm128(const u16* __restrict__ A, const u16* __restrict__ Bt,
             const float* __restrict__ bias, const u16* __restrict__ resid,
             void* __restrict__ Cout, int M, int N, int K, int lda, int ldb,
             int tx, int ty, long long batchA, long long batchB, long long batchC,
             float scale) {
  __shared__ u16 As[2][128 * TBK];  // 2 x 16 KB
  __shared__ u16 Bs[2][128 * TBK];  // 2 x 16 KB

  // bijective XCD swizzle (m204)
  const int nwg = gridDim.x;
  const int orig = blockIdx.x;
  const int q = nwg >> 3, r = nwg & 7;
  const int xcd = orig & 7, idx = orig >> 3;
  const int wg = (xcd < r ? xcd * (q + 1) : r * (q + 1) + (xcd - r) * q) + idx;
  const int bx = wg % tx;
  const int tmp = wg / tx;
  const int by = tmp % ty;
  const int b  = tmp / ty;

  const u16* Ab = A + (long)b * batchA;
  const u16* Bb = Bt + (long)b * batchB;
  const int row0 = by * 128;
  const int col0 = bx * 128;
  const int tid = threadIdx.x;
  const int lane = tid & 63, wid = tid >> 6;     // 4 waves
  const int wm = wid >> 1, wn = wid & 1;         // 2M x 2N
  const int rowW = wm * 64;
  const int l15 = lane & 15, g = lane >> 4;

  const int sr = lane >> 3;                  // row within 8-row slice
  const int sc = ((lane & 7) ^ sr) * 8;      // pre-swizzled source chunk
  const int wrow = wid * 8 + sr;             // 0..31

  const int c0 = ((0 + g) ^ (l15 & 7)) * 8;
  const int c1 = ((4 + g) ^ (l15 & 7)) * 8;

  auto stageA = [&](int h, int kt, int bf_) {  // half-tile = 64 rows, 2 issues
#pragma unroll
    for (int j = 0; j < 2; ++j)
      gload16(Ab + (size_t)(row0 + h * 64 + j * 32 + wrow) * lda + kt * TBK + sc,
              &As[bf_][(h * 64 + j * 32 + wid * 8) * TBK]);
  };
  auto stageB = [&](int h, int kt, int bf_) {
#pragma unroll
    for (int j = 0; j < 2; ++j)
      gload16(Bb + (size_t)(col0 + h * 64 + j * 32 + wrow) * ldb + kt * TBK + sc,
              &Bs[bf_][(h * 64 + j * 32 + wid * 8) * TBK]);
  };

  s16x8 af[4][2];
  s16x8 bfr[4][2];
  f32x4 acc[4][4] = {};
  const int nt = K / TBK;

  // prologue: tile0 (A+B) -> buf0, A(1) -> buf1; wait tile0's 8 issues
  stageA(0, 0, 0); stageA(1, 0, 0);
  stageB(0, 0, 0); stageB(1, 0, 0);
  if (nt > 1) {
    stageA(0, 1, 1); stageA(1, 1, 1);
    asm volatile("s_waitcnt vmcnt(4)" ::: "memory");
  } else {
    asm volatile("s_waitcnt vmcnt(0)" ::: "memory");
  }
  __builtin_amdgcn_s_barrier();

  for (int t = 0; t < nt; ++t) {
    const int cur = t & 1;
    const u16* Asc = &As[cur][0];
    const u16* Bsc = &Bs[cur][0];

    // ---- phase A: ALL frag reads; stage B(t+1) -> other buf
#pragma unroll
    for (int nf = 0; nf < 4; ++nf) {
      const int rb = (wn * 64 + nf * 16 + l15) * TBK;
      bfr[nf][0] = *(const s16x8*)(Bsc + rb + c0);
      bfr[nf][1] = *(const s16x8*)(Bsc + rb + c1);
    }
#pragma unroll
    for (int mf = 0; mf < 4; ++mf) {
      const int rb = (rowW + mf * 16 + l15) * TBK;
      af[mf][0] = *(const s16x8*)(Asc + rb + c0);
      af[mf][1] = *(const s16x8*)(Asc + rb + c1);
    }
    if (t + 1 < nt) { stageB(0, t + 1, cur ^ 1); stageB(1, t + 1, cur ^ 1); }
    // pin: my buf[cur] reads complete, then all-wave rendezvous
    asm volatile("s_waitcnt lgkmcnt(0)" ::: "memory");
    __builtin_amdgcn_sched_barrier(0);
    __builtin_amdgcn_s_barrier();
    __builtin_amdgcn_s_setprio(1);
    QUAD(0)
    __builtin_amdgcn_s_setprio(0);
    // ---- phase B: stage A(t+2) -> CURRENT buf; MFMA half 2
    if (t + 2 < nt) { stageA(0, t + 2, cur); stageA(1, t + 2, cur); }
    __builtin_amdgcn_s_setprio(1);
    QUAD(2)
    __builtin_amdgcn_s_setprio(0);
    if (t + 1 < nt) {
      if (t + 2 < nt) asm volatile("s_waitcnt vmcnt(4)" ::: "memory");
      else            asm volatile("s_waitcnt vmcnt(0)" ::: "memory");
      __builtin_amdgcn_s_barrier();
    }
  }

  const long cb = (long)b * batchC;
#pragma unroll
  for (int mf = 0; mf < 4; ++mf) {
    const int rbase = row0 + rowW + mf * 16 + g * 4;
#pragma unroll
    for (int nf = 0; nf < 4; ++nf) {
      const int col = col0 + wn * 64 + nf * 16 + l15;
#pragma unroll
      for (int rr = 0; rr < 4; ++rr)
        epi_store(EPI, Cout, cb + (long)(rbase + rr) * N + col,
                  acc[mf][nf][rr], bias, col, resid, scale);
    }
  }
}

// ---------- per-row top-k threshold + sparse softmax: ONE WAVE PER ROW ----------
__global__ __launch_bounds__(256)
void topk_softmax(const u16* __restrict__ scores, u16* __restrict__ P, int topk) {
  const int lane = threadIdx.x & 63, wid = threadIdx.x >> 6;
  const long row = (long)blockIdx.x * 4 + wid;
  const long rowoff = row * 2048;

  float v[32]; uint32_t kv[32];
  const uint32_t* src = (const uint32_t*)(scores + rowoff);
#pragma unroll
  for (int j = 0; j < 16; ++j) {
    uint32_t w = src[j * 64 + lane];
    v[2 * j]     = bf2f((u16)(w & 0xFFFFu));
    v[2 * j + 1] = bf2f((u16)(w >> 16));
  }
#pragma unroll
  for (int j = 0; j < 32; ++j) {
    union { float f; uint32_t u; } c; c.f = v[j];
    kv[j] = (c.u & 0x80000000u) ? ~c.u : (c.u | 0x80000000u);  // monotonic key
  }
  float m = v[0];
#pragma unroll
  for (int j = 1; j < 32; ++j) m = fmaxf(m, v[j]);
  m = wave_max_f(m);

  uint32_t cur = 0;
  for (int bit = 31; bit >= 16; --bit) {   // 16-bit radix (exact for bf16 keys)
    const uint32_t cand = cur | (1u << bit);
    int c = 0;
#pragma unroll
    for (int j = 0; j < 32; ++j)
      c += (int)__popcll(__ballot(kv[j] >= cand));
    if (c >= topk) cur = cand;
  }

  const float mm = fmaxf(m, 0.0f);
  float p[32], s = 0.0f;
#pragma unroll
  for (int j = 0; j < 32; ++j) {
    float val = (kv[j] >= cur) ? v[j] : 0.0f;
    p[j] = __expf(val - mm);
    s += p[j];
  }
  s = wave_sum_f(s);
  const float inv = 1.0f / s;
  uint32_t* dst = (uint32_t*)(P + rowoff);
#pragma unroll
  for (int j = 0; j < 16; ++j) {
    uint32_t w = (uint32_t)f2bf(p[2 * j] * inv) |
                 ((uint32_t)f2bf(p[2 * j + 1] * inv) << 16);
    dst[j * 64 + lane] = w;
  }
}

// ---------- fused (a [+ bf16 r]) -> LayerNorm; a is fp32 OR bf16 ----------
__global__ __launch_bounds__(256)
void add_ln(const float* __restrict__ af, const u16* __restrict__ ab,
            const u16* __restrict__ r,
            const float* __restrict__ gamma, const float* __restrict__ beta,
            float* __restrict__ outf, u16* __restrict__ outb) {
  const long off = (long)blockIdx.x * 1024;
  const int tid = threadIdx.x, lane = tid & 63, wid = tid >> 6;
  const int c4 = tid * 4;
  __shared__ float sred[4];
  float x[4];
  if (af) {
    f32x4 av = *(const f32x4*)(af + off + c4);
#pragma unroll
    for (int j = 0; j < 4; ++j) x[j] = av[j];
  } else {
    u16x4 av = *(const u16x4*)(ab + off + c4);
#pragma unroll
    for (int j = 0; j < 4; ++j) x[j] = bf2f(av[j]);
  }
  if (r) {
    u16x4 rv = *(const u16x4*)(r + off + c4);
#pragma unroll
    for (int j = 0; j < 4; ++j) x[j] += bf2f(rv[j]);
  }
  float s = x[0] + x[1] + x[2] + x[3];
  s = wave_sum_f(s);
  if (lane == 0) sred[wid] = s;
  __syncthreads();
  float mu = (sred[0] + sred[1] + sred[2] + sred[3]) * (1.0f / 1024.0f);
  __syncthreads();
  float qv = 0.0f;
#pragma unroll
  for (int j = 0; j < 4; ++j) { float d = x[j] - mu; qv += d * d; }
  qv = wave_sum_f(qv);
  if (lane == 0) sred[wid] = qv;
  __syncthreads();
  float var = (sred[0] + sred[1] + sred[2] + sred[3]) * (1.0f / 1024.0f);
  float inv = rsqrtf(var + 1e-6f);
  f32x4 gv = *(const f32x4*)(gamma + c4);
  f32x4 bv = *(const f32x4*)(beta + c4);
  f32x4 ov; u16x4 ob;
#pragma unroll
  for (int j = 0; j < 4; ++j) {
    float o = (x[j] - mu) * inv * gv[j] + bv[j];
    ov[j] = o; ob[j] = f2bf(o);
  }
  if (outf) *(f32x4*)(outf + off + c4) = ov;
  if (outb) *(u16x4*)(outb + off + c4) = ob;
}

// ---------- launch ----------
extern "C" void kernel_launch(void* const* d_in, const int* in_sizes, int n_in,
                              void* d_out, int out_size, void* d_ws, size_t ws_size,
                              hipStream_t stream) {
  const float* x   = (const float*)d_in[0];
  const float* Wq  = (const float*)d_in[1];
  const float* bq  = (const float*)d_in[2];
  const float* Wk  = (const float*)d_in[3];
  const float* bk  = (const float*)d_in[4];
  const float* Wv  = (const float*)d_in[5];
  const float* bv  = (const float*)d_in[6];
  const float* W1  = (const float*)d_in[7];
  const float* b1  = (const float*)d_in[8];
  const float* W2  = (const float*)d_in[9];
  const float* b2  = (const float*)d_in[10];
  const float* g1  = (const float*)d_in[11];
  const float* be1 = (const float*)d_in[12];
  const float* g2  = (const float*)d_in[13];
  const float* be2 = (const float*)d_in[14];

  const int Bz = 4, S = 2048, Dm = 1024, Ff = 4096;
  const int M = Bz * S; // 8192
  const int N3 = 3 * Dm; // 3072

  char* ws = (char*)d_ws;
  const size_t MBy = 1024u * 1024u;
  u16*  wqkvT  = (u16*)(ws + 0 * MBy);     // 6 MB  [3072][1024]
  u16*  w1T    = (u16*)(ws + 6 * MBy);     // 8 MB  [Ff][Dm]
  u16*  w2T    = (u16*)(ws + 14 * MBy);    // 8 MB  [Dm][Ff]
  u16*  xbf    = (u16*)(ws + 23 * MBy);    // 16 MB
  u16*  qkv    = (u16*)(ws + 39 * MBy);    // 48 MB [8192][3072] fused q|k|v
  u16*  vT     = (u16*)(ws + 87 * MBy);    // 16 MB [B][Dm][S]
  float* bqkv  = (float*)(ws + 103 * MBy); // 12 KB (live only during QKV GEMM)
  u16*  scores = (u16*)(ws + 103 * MBy);   // 32 MB [B][S][S] bf16 (after QKV done)
  u16*  P      = (u16*)(ws + 167 * MBy);   // 32 MB
  u16*  attn   = (u16*)(ws + 135 * MBy);   // 16 MB bf16
  u16*  out1b  = (u16*)(ws + 23 * MBy);    // 16 MB (reuse xbf; x dead after QKV)
  u16*  y      = (u16*)(ws + 167 * MBy);   // 16 MB bf16 (reuse P; P dead after PV)

  dim3 blk(256);
  dim3 blk8(512);

  // casts / weight prep
  cast_f32_bf16<<<dim3((unsigned)((long)M * Dm / 1024)), blk, 0, stream>>>(x, xbf);
  transpose_cast_f32_bf16<<<dim3(Dm / 32, Dm / 32), blk, 0, stream>>>(Wq, wqkvT, Dm, Dm);
  transpose_cast_f32_bf16<<<dim3(Dm / 32, Dm / 32), blk, 0, stream>>>(Wk, wqkvT + 1024 * 1024, Dm, Dm);
  transpose_cast_f32_bf16<<<dim3(Dm / 32, Dm / 32), blk, 0, stream>>>(Wv, wqkvT + 2048 * 1024, Dm, Dm);
  transpose_cast_f32_bf16<<<dim3(Ff / 32, Dm / 32), blk, 0, stream>>>(W1, w1T, Dm, Ff);
  transpose_cast_f32_bf16<<<dim3(Dm / 32, Ff / 32), blk, 0, stream>>>(W2, w2T, Ff, Dm);
  concat3<<<dim3(12), blk, 0, stream>>>(bq, bk, bv, bqkv);

  // fused QKV projection: [M][3072] = xbf @ wqkvT^T + bqkv  (128^2: 24x64=1536 blocks)
  gemm128<EPI_BF16_BIAS><<<dim3(24 * 64), blk, 0, stream>>>(
      xbf, wqkvT, bqkv, nullptr, qkv, M, N3, Dm, Dm, Dm, 24, 64, 0, 0, 0, 1.0f);

  // v slice -> v^T per batch for PV GEMM
  transpose_bf16<<<dim3(Dm / 32, S / 32, Bz), blk, 0, stream>>>(
      qkv + 2048, vT, S, Dm, N3, (long)S * N3, (long)Dm * S);

  // scores[b] = q[b] @ k[b]^T / sqrt(Dm) -> bf16   (256^2: 8x8x4=256 blocks; R11-best)
  gemm8p<EPI_BF16_SCALE><<<dim3(8 * 8 * Bz), blk8, 0, stream>>>(
      qkv, qkv + 1024, nullptr, nullptr, scores, S, S, Dm, N3, N3, 8, 8,
      (long long)S * N3, (long long)S * N3, (long long)S * S, 0.03125f);

  // top-k threshold + sparse softmax -> P (bf16): one wave per row
  topk_softmax<<<dim3(Bz * S / 4), blk, 0, stream>>>(scores, P, S / 2);

  // attn_out[b] = P[b] @ v[b] -> bf16   (128^2: 8x16x4=512 blocks)
  gemm128<EPI_BF16><<<dim3(8 * 16 * Bz), blk, 0, stream>>>(
      P, vT, nullptr, nullptr, attn, S, Dm, S, S, S, 8, 16,
      (long long)S * S, (long long)Dm * S, (long long)S * Dm, 1.0f);

  // out1 = LN(x + attn_out) -> bf16 only
  add_ln<<<dim3(M), blk, 0, stream>>>(x, nullptr, attn, g1, be1, nullptr, out1b);

  // h = relu(out1 @ W1 + b1) -> bf16   (128^2: 32x64=2048 blocks; R12-best)
  gemm128<EPI_RELU_BF16_BIAS><<<dim3(32 * 64), blk, 0, stream>>>(
      out1b, w1T, b1, nullptr, qkv /*hbf reuse*/, M, Ff, Dm, Dm, Dm, 32, 64, 0, 0, 0, 1.0f);

  // y = h @ W2 + b2 + out1 (bf16 resid) -> bf16   (128^2: 8x64=512 blocks)
  gemm128<EPI_BF16_BIAS_RESIDBF><<<dim3(8 * 64), blk, 0, stream>>>(
      qkv /*hbf*/, w2T, b2, out1b, y, M, Dm, Ff, Ff, Ff, 8, 64, 0, 0, 0, 1.0f);

  // out = LN(y)  (y bf16)
  add_ln<<<dim3(M), blk, 0, stream>>>(nullptr, y, nullptr, g2, be2, (float*)d_out, nullptr);
}

// Round 16
// 349.456 us; speedup vs baseline: 1.0208x; 1.0208x over previous
//
#include <hip/hip_runtime.h>
#include <cstdint>

typedef unsigned short u16;
typedef __attribute__((ext_vector_type(8))) short s16x8;   // 8 bf16 (4 VGPR) MFMA A/B frag
typedef __attribute__((ext_vector_type(4))) unsigned short u16x4;
typedef __attribute__((ext_vector_type(4))) float f32x4;   // MFMA C/D frag

// ---------- helpers ----------
__device__ __forceinline__ u16 f2bf(float f) {
  union { float f; uint32_t u; } c; c.f = f;
  uint32_t r = c.u + 0x7FFFu + ((c.u >> 16) & 1u);   // RNE
  return (u16)(r >> 16);
}
__device__ __forceinline__ float bf2f(u16 b) {
  union { uint32_t u; float f; } c; c.u = ((uint32_t)b) << 16;
  return c.f;
}
__device__ __forceinline__ float wave_sum_f(float v) {
#pragma unroll
  for (int o = 32; o > 0; o >>= 1) v += __shfl_xor(v, o);
  return v;
}
__device__ __forceinline__ float wave_max_f(float v) {
#pragma unroll
  for (int o = 32; o > 0; o >>= 1) v = fmaxf(v, __shfl_xor(v, o));
  return v;
}
// async global->LDS, 16B per lane, wave-uniform LDS base (+lane*16 implicit)
__device__ __forceinline__ void gload16(const u16* g, u16* l) {
  __builtin_amdgcn_global_load_lds(
      (const __attribute__((address_space(1))) unsigned int*)g,
      (__attribute__((address_space(3))) unsigned int*)l,
      16, 0, 0);
}

// ---------- elementwise cast fp32 -> bf16 ----------
__global__ __launch_bounds__(256)
void cast_f32_bf16(const float* __restrict__ in, u16* __restrict__ out) {
  long i = ((long)blockIdx.x * 256 + threadIdx.x) * 4;
  f32x4 v = *(const f32x4*)(in + i);
  u16x4 o;
#pragma unroll
  for (int j = 0; j < 4; ++j) o[j] = f2bf(v[j]);
  *(u16x4*)(out + i) = o;
}

// ---------- concat 3 bias vectors (1024 each) ----------
__global__ __launch_bounds__(256)
void concat3(const float* __restrict__ a, const float* __restrict__ b,
             const float* __restrict__ c, float* __restrict__ o) {
  int i = blockIdx.x * 256 + threadIdx.x;
  o[i] = i < 1024 ? a[i] : (i < 2048 ? b[i - 1024] : c[i - 2048]);
}

// ---------- cast+transpose fp32 [R][C] -> bf16 [C][R] ----------
__global__ __launch_bounds__(256)
void transpose_cast_f32_bf16(const float* __restrict__ in, u16* __restrict__ out,
                             int R, int C) {
  __shared__ float tile[32][33];
  int r0 = blockIdx.y * 32, c0 = blockIdx.x * 32;
  int tid = threadIdx.x;
  int tr = tid >> 3, tc4 = (tid & 7) * 4;
  f32x4 v = *(const f32x4*)(in + (long)(r0 + tr) * C + c0 + tc4);
#pragma unroll
  for (int j = 0; j < 4; ++j) tile[tr][tc4 + j] = v[j];
  __syncthreads();
  u16x4 o;
#pragma unroll
  for (int j = 0; j < 4; ++j) o[j] = f2bf(tile[tc4 + j][tr]);
  *(u16x4*)(out + (long)(c0 + tr) * R + r0 + tc4) = o;
}

// ---------- strided transpose bf16: in[z][r][c] (row stride in_rs) -> out[z][c][r] ----------
__global__ __launch_bounds__(256)
void transpose_bf16(const u16* __restrict__ in, u16* __restrict__ out,
                    int R, int C, int in_rs, long in_batch, long out_batch) {
  __shared__ u16 tile[32][36];
  const long zin = (long)blockIdx.z * in_batch;
  const long zout = (long)blockIdx.z * out_batch;
  int r0 = blockIdx.y * 32, c0 = blockIdx.x * 32;
  int tid = threadIdx.x;
  int tr = tid >> 3, tc4 = (tid & 7) * 4;
  u16x4 v = *(const u16x4*)(in + zin + (long)(r0 + tr) * in_rs + c0 + tc4);
#pragma unroll
  for (int j = 0; j < 4; ++j) tile[tr][tc4 + j] = v[j];
  __syncthreads();
  u16x4 o;
#pragma unroll
  for (int j = 0; j < 4; ++j) o[j] = tile[tc4 + j][tr];
  *(u16x4*)(out + zout + (long)(c0 + tr) * R + r0 + tc4) = o;
}

#define TBM 256
#define TBK 64

enum { EPI_BF16_BIAS = 0, EPI_BF16_SCALE = 1, EPI_BF16 = 2,
       EPI_RELU_BF16_BIAS = 3, EPI_BF16_BIAS_RESIDBF = 4 };

#define QUAD(MFA)                                                             \
  _Pragma("unroll")                                                           \
  for (int mf = (MFA); mf < (MFA) + 2; ++mf)                                  \
    _Pragma("unroll")                                                         \
    for (int nf = 0; nf < 4; ++nf) {                                          \
      acc[mf][nf] = __builtin_amdgcn_mfma_f32_16x16x32_bf16(                  \
          af[mf][0], bfr[nf][0], acc[mf][nf], 0, 0, 0);                       \
      acc[mf][nf] = __builtin_amdgcn_mfma_f32_16x16x32_bf16(                  \
          af[mf][1], bfr[nf][1], acc[mf][nf], 0, 0, 0);                       \
    }

__device__ __forceinline__ void epi_store(int EPIv, void* Cout, long cidx,
                                          float v, const float* bias, int col,
                                          const u16* resid, float scale) {
  if (EPIv == EPI_BF16_BIAS) {
    ((u16*)Cout)[cidx] = f2bf(v + bias[col]);
  } else if (EPIv == EPI_BF16_SCALE) {
    ((u16*)Cout)[cidx] = f2bf(v * scale);
  } else if (EPIv == EPI_BF16) {
    ((u16*)Cout)[cidx] = f2bf(v);
  } else if (EPIv == EPI_RELU_BF16_BIAS) {
    ((u16*)Cout)[cidx] = f2bf(fmaxf(v + bias[col], 0.0f));
  } else { // EPI_BF16_BIAS_RESIDBF
    ((u16*)Cout)[cidx] = f2bf(v + bias[col] + bf2f(resid[cidx]));
  }
}

// ---------- 8-wave 256x256 MFMA GEMM (R11-measured best for scores+FFN1) ----------
template <int EPI>
__global__ __launch_bounds__(512, 2)
void gemm8p(const u16* __restrict__ A, const u16* __restrict__ Bt,
            const float* __restrict__ bias, const u16* __restrict__ resid,
            void* __restrict__ Cout, int M, int N, int K, int lda, int ldb,
            int tx, int ty, long long batchA, long long batchB, long long batchC,
            float scale) {
  constexpr int BN_ = 256;
  constexpr int MF = 8;
  __shared__ u16 As[2][TBM * TBK];  // 2 x 32 KB
  __shared__ u16 Bs[2][BN_ * TBK];  // 2 x 32 KB

  // bijective XCD swizzle (m204)
  const int nwg = gridDim.x;
  const int orig = blockIdx.x;
  const int q = nwg >> 3, r = nwg & 7;
  const int xcd = orig & 7, idx = orig >> 3;
  const int wg = (xcd < r ? xcd * (q + 1) : r * (q + 1) + (xcd - r) * q) + idx;
  const int bx = wg % tx;
  const int tmp = wg / tx;
  const int by = tmp % ty;
  const int b  = tmp / ty;

  const u16* Ab = A + (long)b * batchA;
  const u16* Bb = Bt + (long)b * batchB;
  const int row0 = by * TBM;
  const int col0 = bx * BN_;
  const int tid = threadIdx.x;
  const int lane = tid & 63, wid = tid >> 6;     // 8 waves
  const int wm = wid >> 2, wn = wid & 3;         // 2M x 4N
  const int rowW = wm * 128;
  const int l15 = lane & 15, g = lane >> 4;

  const int sr = lane >> 3;
  const int sc = ((lane & 7) ^ sr) * 8;
  const int wrow = wid * 8 + sr;

  const int c0 = ((0 + g) ^ (l15 & 7)) * 8;
  const int c1 = ((4 + g) ^ (l15 & 7)) * 8;

  auto stageA = [&](int h, int kt, int bf_) {
#pragma unroll
    for (int j = 0; j < 2; ++j)
      gload16(Ab + (size_t)(row0 + h * 128 + j * 64 + wrow) * lda + kt * TBK + sc,
              &As[bf_][(h * 128 + j * 64 + wid * 8) * TBK]);
  };
  auto stageB = [&](int h, int kt, int bf_) {
#pragma unroll
    for (int j = 0; j < 2; ++j)
      gload16(Bb + (size_t)(col0 + h * 128 + j * 64 + wrow) * ldb + kt * TBK + sc,
              &Bs[bf_][(h * 128 + j * 64 + wid * 8) * TBK]);
  };

  s16x8 af[MF][2];
  s16x8 bfr[4][2];
  f32x4 acc[MF][4] = {};
  const int nt = K / TBK;

  stageA(0, 0, 0); stageA(1, 0, 0);
  stageB(0, 0, 0); stageB(1, 0, 0);
  if (nt > 1) {
    stageA(0, 1, 1); stageA(1, 1, 1);
    asm volatile("s_waitcnt vmcnt(4)" ::: "memory");
  } else {
    asm volatile("s_waitcnt vmcnt(0)" ::: "memory");
  }
  __builtin_amdgcn_s_barrier();

  for (int t = 0; t < nt; ++t) {
    const int cur = t & 1;
    const u16* Asc = &As[cur][0];
    const u16* Bsc = &Bs[cur][0];

    // ---- phase 0
#pragma unroll
    for (int nf = 0; nf < 4; ++nf) {
      const int rb = (wn * 64 + nf * 16 + l15) * TBK;
      bfr[nf][0] = *(const s16x8*)(Bsc + rb + c0);
      bfr[nf][1] = *(const s16x8*)(Bsc + rb + c1);
    }
#pragma unroll
    for (int mf = 0; mf < 4; ++mf) {
      const int rb = (rowW + mf * 16 + l15) * TBK;
      af[mf][0] = *(const s16x8*)(Asc + rb + c0);
      af[mf][1] = *(const s16x8*)(Asc + rb + c1);
    }
    if (t + 1 < nt) stageB(0, t + 1, cur ^ 1);
    __builtin_amdgcn_s_barrier();
    __builtin_amdgcn_s_setprio(1);
    QUAD(0)
    __builtin_amdgcn_s_setprio(0);
    __builtin_amdgcn_s_barrier();

    // ---- phase 1
#pragma unroll
    for (int mf = 4; mf < 8; ++mf) {
      const int rb = (rowW + mf * 16 + l15) * TBK;
      af[mf][0] = *(const s16x8*)(Asc + rb + c0);
      af[mf][1] = *(const s16x8*)(Asc + rb + c1);
    }
    if (t + 1 < nt) stageB(1, t + 1, cur ^ 1);
    __builtin_amdgcn_s_barrier();
    __builtin_amdgcn_s_setprio(1);
    QUAD(2)
    __builtin_amdgcn_s_setprio(0);
    asm volatile("s_waitcnt lgkmcnt(0)" ::: "memory");
    __builtin_amdgcn_sched_barrier(0);
    __builtin_amdgcn_s_barrier();

    // ---- phase 2
    if (t + 2 < nt) stageA(0, t + 2, cur);
    __builtin_amdgcn_s_barrier();
    __builtin_amdgcn_s_setprio(1);
    QUAD(4)
    __builtin_amdgcn_s_setprio(0);
    __builtin_amdgcn_s_barrier();

    // ---- phase 3
    if (t + 2 < nt) stageA(1, t + 2, cur);
    __builtin_amdgcn_s_barrier();
    __builtin_amdgcn_s_setprio(1);
    QUAD(6)
    __builtin_amdgcn_s_setprio(0);
    if (t + 1 < nt) {
      if (t + 2 < nt) asm volatile("s_waitcnt vmcnt(4)" ::: "memory");
      else            asm volatile("s_waitcnt vmcnt(0)" ::: "memory");
    }
    __builtin_amdgcn_s_barrier();
  }

  const long cb = (long)b * batchC;
#pragma unroll
  for (int mf = 0; mf < MF; ++mf) {
    const int rbase = row0 + rowW + mf * 16 + g * 4;
#pragma unroll
    for (int nf = 0; nf < 4; ++nf) {
      const int col = col0 + wn * 64 + nf * 16 + l15;
#pragma unroll
      for (int rr = 0; rr < 4; ++rr)
        epi_store(EPI, Cout, cb + (long)(rbase + rr) * N + col,
                  acc[mf][nf][rr], bias, col, resid, scale);
    }
  }
}

// ---------- 4-wave 128x128 MFMA GEMM: 2 blocks/CU, 2-phase counted-vmcnt ----------
template <int EPI>
__global__ __launch_bounds__(256, 2)
void gemm128(const u16* __restrict__ A, const u16* __restrict__ Bt,
             const float* __restrict__ bias, const u16* __restrict__ resid,
             void* __restrict__ Cout, int M, int N, int K, int lda, int ldb,
             int tx, int ty, long long batchA, long long batchB, long long batchC,
             float scale) {
  __shared__ u16 As[2][128 * TBK];  // 2 x 16 KB
  __shared__ u16 Bs[2][128 * TBK];  // 2 x 16 KB

  // bijective XCD swizzle (m204)
  const int nwg = gridDim.x;
  const int orig = blockIdx.x;
  const int q = nwg >> 3, r = nwg & 7;
  const int xcd = orig & 7, idx = orig >> 3;
  const int wg = (xcd < r ? xcd * (q + 1) : r * (q + 1) + (xcd - r) * q) + idx;
  const int bx = wg % tx;
  const int tmp = wg / tx;
  const int by = tmp % ty;
  const int b  = tmp / ty;

  const u16* Ab = A + (long)b * batchA;
  const u16* Bb = Bt + (long)b * batchB;
  const int row0 = by * 128;
  const int col0 = bx * 128;
  const int tid = threadIdx.x;
  const int lane = tid & 63, wid = tid >> 6;     // 4 waves
  const int wm = wid >> 1, wn = wid & 1;         // 2M x 2N
  const int rowW = wm * 64;
  const int l15 = lane & 15, g = lane >> 4;

  const int sr = lane >> 3;                  // row within 8-row slice
  const int sc = ((lane & 7) ^ sr) * 8;      // pre-swizzled source chunk
  const int wrow = wid * 8 + sr;             // 0..31

  const int c0 = ((0 + g) ^ (l15 & 7)) * 8;
  const int c1 = ((4 + g) ^ (l15 & 7)) * 8;

  auto stageA = [&](int h, int kt, int bf_) {  // half-tile = 64 rows, 2 issues
#pragma unroll
    for (int j = 0; j < 2; ++j)
      gload16(Ab + (size_t)(row0 + h * 64 + j * 32 + wrow) * lda + kt * TBK + sc,
              &As[bf_][(h * 64 + j * 32 + wid * 8) * TBK]);
  };
  auto stageB = [&](int h, int kt, int bf_) {
#pragma unroll
    for (int j = 0; j < 2; ++j)
      gload16(Bb + (size_t)(col0 + h * 64 + j * 32 + wrow) * ldb + kt * TBK + sc,
              &Bs[bf_][(h * 64 + j * 32 + wid * 8) * TBK]);
  };

  s16x8 af[4][2];
  s16x8 bfr[4][2];
  f32x4 acc[4][4] = {};
  const int nt = K / TBK;

  // prologue: tile0 (A+B) -> buf0, A(1) -> buf1; wait tile0's 8 issues
  stageA(0, 0, 0); stageA(1, 0, 0);
  stageB(0, 0, 0); stageB(1, 0, 0);
  if (nt > 1) {
    stageA(0, 1, 1); stageA(1, 1, 1);
    asm volatile("s_waitcnt vmcnt(4)" ::: "memory");
  } else {
    asm volatile("s_waitcnt vmcnt(0)" ::: "memory");
  }
  __builtin_amdgcn_s_barrier();

  for (int t = 0; t < nt; ++t) {
    const int cur = t & 1;
    const u16* Asc = &As[cur][0];
    const u16* Bsc = &Bs[cur][0];

    // ---- phase A: ALL frag reads; stage B(t+1) -> other buf
#pragma unroll
    for (int nf = 0; nf < 4; ++nf) {
      const int rb = (wn * 64 + nf * 16 + l15) * TBK;
      bfr[nf][0] = *(const s16x8*)(Bsc + rb + c0);
      bfr[nf][1] = *(const s16x8*)(Bsc + rb + c1);
    }
#pragma unroll
    for (int mf = 0; mf < 4; ++mf) {
      const int rb = (rowW + mf * 16 + l15) * TBK;
      af[mf][0] = *(const s16x8*)(Asc + rb + c0);
      af[mf][1] = *(const s16x8*)(Asc + rb + c1);
    }
    if (t + 1 < nt) { stageB(0, t + 1, cur ^ 1); stageB(1, t + 1, cur ^ 1); }
    // pin: my buf[cur] reads complete, then all-wave rendezvous
    asm volatile("s_waitcnt lgkmcnt(0)" ::: "memory");
    __builtin_amdgcn_sched_barrier(0);
    __builtin_amdgcn_s_barrier();
    __builtin_amdgcn_s_setprio(1);
    QUAD(0)
    __builtin_amdgcn_s_setprio(0);
    // ---- phase B: stage A(t+2) -> CURRENT buf; MFMA half 2
    if (t + 2 < nt) { stageA(0, t + 2, cur); stageA(1, t + 2, cur); }
    __builtin_amdgcn_s_setprio(1);
    QUAD(2)
    __builtin_amdgcn_s_setprio(0);
    if (t + 1 < nt) {
      if (t + 2 < nt) asm volatile("s_waitcnt vmcnt(4)" ::: "memory");
      else            asm volatile("s_waitcnt vmcnt(0)" ::: "memory");
      __builtin_amdgcn_s_barrier();
    }
  }

  const long cb = (long)b * batchC;
#pragma unroll
  for (int mf = 0; mf < 4; ++mf) {
    const int rbase = row0 + rowW + mf * 16 + g * 4;
#pragma unroll
    for (int nf = 0; nf < 4; ++nf) {
      const int col = col0 + wn * 64 + nf * 16 + l15;
#pragma unroll
      for (int rr = 0; rr < 4; ++rr)
        epi_store(EPI, Cout, cb + (long)(rbase + rr) * N + col,
                  acc[mf][nf][rr], bias, col, resid, scale);
    }
  }
}

// ---------- per-row top-k threshold + sparse softmax: ONE WAVE PER ROW ----------
__global__ __launch_bounds__(256)
void topk_softmax(const u16* __restrict__ scores, u16* __restrict__ P, int topk) {
  const int lane = threadIdx.x & 63, wid = threadIdx.x >> 6;
  const long row = (long)blockIdx.x * 4 + wid;
  const long rowoff = row * 2048;

  float v[32]; uint32_t kv[32];
  const uint32_t* src = (const uint32_t*)(scores + rowoff);
#pragma unroll
  for (int j = 0; j < 16; ++j) {
    uint32_t w = src[j * 64 + lane];
    v[2 * j]     = bf2f((u16)(w & 0xFFFFu));
    v[2 * j + 1] = bf2f((u16)(w >> 16));
  }
#pragma unroll
  for (int j = 0; j < 32; ++j) {
    union { float f; uint32_t u; } c; c.f = v[j];
    kv[j] = (c.u & 0x80000000u) ? ~c.u : (c.u | 0x80000000u);  // monotonic key
  }
  float m = v[0];
#pragma unroll
  for (int j = 1; j < 32; ++j) m = fmaxf(m, v[j]);
  m = wave_max_f(m);

  uint32_t cur = 0;
  for (int bit = 31; bit >= 16; --bit) {   // 16-bit radix (exact for bf16 keys)
    const uint32_t cand = cur | (1u << bit);
    int c = 0;
#pragma unroll
    for (int j = 0; j < 32; ++j)
      c += (int)__popcll(__ballot(kv[j] >= cand));
    if (c >= topk) cur = cand;
  }

  const float mm = fmaxf(m, 0.0f);
  float p[32], s = 0.0f;
#pragma unroll
  for (int j = 0; j < 32; ++j) {
    float val = (kv[j] >= cur) ? v[j] : 0.0f;
    p[j] = __expf(val - mm);
    s += p[j];
  }
  s = wave_sum_f(s);
  const float inv = 1.0f / s;
  uint32_t* dst = (uint32_t*)(P + rowoff);
#pragma unroll
  for (int j = 0; j < 16; ++j) {
    uint32_t w = (uint32_t)f2bf(p[2 * j] * inv) |
                 ((uint32_t)f2bf(p[2 * j + 1] * inv) << 16);
    dst[j * 64 + lane] = w;
  }
}

// ---------- fused (a [+ bf16 r]) -> LayerNorm; a is fp32 OR bf16 ----------
__global__ __launch_bounds__(256)
void add_ln(const float* __restrict__ af, const u16* __restrict__ ab,
            const u16* __restrict__ r,
            const float* __restrict__ gamma, const float* __restrict__ beta,
            float* __restrict__ outf, u16* __restrict__ outb) {
  const long off = (long)blockIdx.x * 1024;
  const int tid = threadIdx.x, lane = tid & 63, wid = tid >> 6;
  const int c4 = tid * 4;
  __shared__ float sred[4];
  float x[4];
  if (af) {
    f32x4 av = *(const f32x4*)(af + off + c4);
#pragma unroll
    for (int j = 0; j < 4; ++j) x[j] = av[j];
  } else {
    u16x4 av = *(const u16x4*)(ab + off + c4);
#pragma unroll
    for (int j = 0; j < 4; ++j) x[j] = bf2f(av[j]);
  }
  if (r) {
    u16x4 rv = *(const u16x4*)(r + off + c4);
#pragma unroll
    for (int j = 0; j < 4; ++j) x[j] += bf2f(rv[j]);
  }
  float s = x[0] + x[1] + x[2] + x[3];
  s = wave_sum_f(s);
  if (lane == 0) sred[wid] = s;
  __syncthreads();
  float mu = (sred[0] + sred[1] + sred[2] + sred[3]) * (1.0f / 1024.0f);
  __syncthreads();
  float qv = 0.0f;
#pragma unroll
  for (int j = 0; j < 4; ++j) { float d = x[j] - mu; qv += d * d; }
  qv = wave_sum_f(qv);
  if (lane == 0) sred[wid] = qv;
  __syncthreads();
  float var = (sred[0] + sred[1] + sred[2] + sred[3]) * (1.0f / 1024.0f);
  float inv = rsqrtf(var + 1e-6f);
  f32x4 gv = *(const f32x4*)(gamma + c4);
  f32x4 bv = *(const f32x4*)(beta + c4);
  f32x4 ov; u16x4 ob;
#pragma unroll
  for (int j = 0; j < 4; ++j) {
    float o = (x[j] - mu) * inv * gv[j] + bv[j];
    ov[j] = o; ob[j] = f2bf(o);
  }
  if (outf) *(f32x4*)(outf + off + c4) = ov;
  if (outb) *(u16x4*)(outb + off + c4) = ob;
}

// ---------- launch ----------
extern "C" void kernel_launch(void* const* d_in, const int* in_sizes, int n_in,
                              void* d_out, int out_size, void* d_ws, size_t ws_size,
                              hipStream_t stream) {
  const float* x   = (const float*)d_in[0];
  const float* Wq  = (const float*)d_in[1];
  const float* bq  = (const float*)d_in[2];
  const float* Wk  = (const float*)d_in[3];
  const float* bk  = (const float*)d_in[4];
  const float* Wv  = (const float*)d_in[5];
  const float* bv  = (const float*)d_in[6];
  const float* W1  = (const float*)d_in[7];
  const float* b1  = (const float*)d_in[8];
  const float* W2  = (const float*)d_in[9];
  const float* b2  = (const float*)d_in[10];
  const float* g1  = (const float*)d_in[11];
  const float* be1 = (const float*)d_in[12];
  const float* g2  = (const float*)d_in[13];
  const float* be2 = (const float*)d_in[14];

  const int Bz = 4, S = 2048, Dm = 1024, Ff = 4096;
  const int M = Bz * S; // 8192
  const int N3 = 3 * Dm; // 3072

  char* ws = (char*)d_ws;
  const size_t MBy = 1024u * 1024u;
  u16*  wqkvT  = (u16*)(ws + 0 * MBy);     // 6 MB  [3072][1024]
  u16*  w1T    = (u16*)(ws + 6 * MBy);     // 8 MB  [Ff][Dm]
  u16*  w2T    = (u16*)(ws + 14 * MBy);    // 8 MB  [Dm][Ff]
  u16*  xbf    = (u16*)(ws + 23 * MBy);    // 16 MB (live through LN1)
  u16*  qkv    = (u16*)(ws + 39 * MBy);    // 48 MB [8192][3072] fused q|k|v
  u16*  vT     = (u16*)(ws + 87 * MBy);    // 16 MB [B][Dm][S]
  float* bqkv  = (float*)(ws + 103 * MBy); // 12 KB (live only during QKV GEMM)
  u16*  scores = (u16*)(ws + 103 * MBy);   // 32 MB [B][S][S] bf16 (after QKV done)
  u16*  P      = (u16*)(ws + 167 * MBy);   // 32 MB
  u16*  attn   = (u16*)(ws + 135 * MBy);   // 16 MB bf16
  u16*  out1b  = (u16*)(ws + 151 * MBy);   // 16 MB (own slab; xbf stays live)
  u16*  y      = (u16*)(ws + 167 * MBy);   // 16 MB bf16 (reuse P; P dead after PV)

  dim3 blk(256);
  dim3 blk8(512);

  // casts / weight prep (plain-pointer launches; no H2D copies)
  cast_f32_bf16<<<dim3((unsigned)((long)M * Dm / 1024)), blk, 0, stream>>>(x, xbf);
  transpose_cast_f32_bf16<<<dim3(Dm / 32, Dm / 32), blk, 0, stream>>>(Wq, wqkvT, Dm, Dm);
  transpose_cast_f32_bf16<<<dim3(Dm / 32, Dm / 32), blk, 0, stream>>>(Wk, wqkvT + 1024 * 1024, Dm, Dm);
  transpose_cast_f32_bf16<<<dim3(Dm / 32, Dm / 32), blk, 0, stream>>>(Wv, wqkvT + 2048 * 1024, Dm, Dm);
  transpose_cast_f32_bf16<<<dim3(Ff / 32, Dm / 32), blk, 0, stream>>>(W1, w1T, Dm, Ff);
  transpose_cast_f32_bf16<<<dim3(Dm / 32, Ff / 32), blk, 0, stream>>>(W2, w2T, Ff, Dm);
  concat3<<<dim3(12), blk, 0, stream>>>(bq, bk, bv, bqkv);

  // fused QKV projection: [M][3072] = xbf @ wqkvT^T + bqkv  (128^2: 24x64=1536 blocks)
  gemm128<EPI_BF16_BIAS><<<dim3(24 * 64), blk, 0, stream>>>(
      xbf, wqkvT, bqkv, nullptr, qkv, M, N3, Dm, Dm, Dm, 24, 64, 0, 0, 0, 1.0f);

  // v slice -> v^T per batch for PV GEMM
  transpose_bf16<<<dim3(Dm / 32, S / 32, Bz), blk, 0, stream>>>(
      qkv + 2048, vT, S, Dm, N3, (long)S * N3, (long)Dm * S);

  // scores[b] = q[b] @ k[b]^T / sqrt(Dm) -> bf16   (256^2: 8x8x4=256 blocks; R11-best)
  gemm8p<EPI_BF16_SCALE><<<dim3(8 * 8 * Bz), blk8, 0, stream>>>(
      qkv, qkv + 1024, nullptr, nullptr, scores, S, S, Dm, N3, N3, 8, 8,
      (long long)S * N3, (long long)S * N3, (long long)S * S, 0.03125f);

  // top-k threshold + sparse softmax -> P (bf16): one wave per row
  topk_softmax<<<dim3(Bz * S / 4), blk, 0, stream>>>(scores, P, S / 2);

  // attn_out[b] = P[b] @ v[b] -> bf16   (128^2: 8x16x4=512 blocks)
  gemm128<EPI_BF16><<<dim3(8 * 16 * Bz), blk, 0, stream>>>(
      P, vT, nullptr, nullptr, attn, S, Dm, S, S, S, 8, 16,
      (long long)S * S, (long long)Dm * S, (long long)S * Dm, 1.0f);

  // out1 = LN(xbf + attn_out) -> bf16 only (both inputs bf16)
  add_ln<<<dim3(M), blk, 0, stream>>>(nullptr, xbf, attn, g1, be1, nullptr, out1b);

  // h = relu(out1 @ W1 + b1) -> bf16   (256^2: 16x32=512 blocks; R11-best)
  gemm8p<EPI_RELU_BF16_BIAS><<<dim3(16 * 32), blk8, 0, stream>>>(
      out1b, w1T, b1, nullptr, qkv /*hbf reuse*/, M, Ff, Dm, Dm, Dm, 16, 32, 0, 0, 0, 1.0f);

  // y = h @ W2 + b2 + out1 (bf16 resid) -> bf16   (128^2: 8x64=512 blocks)
  gemm128<EPI_BF16_BIAS_RESIDBF><<<dim3(8 * 64), blk, 0, stream>>>(
      qkv /*hbf*/, w2T, b2, out1b, y, M, Dm, Ff, Ff, Ff, 8, 64, 0, 0, 0, 1.0f);

  // out = LN(y)  (y bf16)
  add_ln<<<dim3(M), blk, 0, stream>>>(nullptr, y, nullptr, g2, be2, (float*)d_out, nullptr);
}

// Round 17
// 346.062 us; speedup vs baseline: 1.0308x; 1.0098x over previous
//
#include <hip/hip_runtime.h>
#include <cstdint>

typedef unsigned short u16;
typedef __attribute__((ext_vector_type(8))) short s16x8;   // 8 bf16 (4 VGPR) MFMA A/B frag
typedef __attribute__((ext_vector_type(4))) unsigned short u16x4;
typedef __attribute__((ext_vector_type(4))) float f32x4;   // MFMA C/D frag

// ---------- helpers ----------
__device__ __forceinline__ u16 f2bf(float f) {
  union { float f; uint32_t u; } c; c.f = f;
  uint32_t r = c.u + 0x7FFFu + ((c.u >> 16) & 1u);   // RNE
  return (u16)(r >> 16);
}
__device__ __forceinline__ float bf2f(u16 b) {
  union { uint32_t u; float f; } c; c.u = ((uint32_t)b) << 16;
  return c.f;
}
__device__ __forceinline__ float wave_sum_f(float v) {
#pragma unroll
  for (int o = 32; o > 0; o >>= 1) v += __shfl_xor(v, o);
  return v;
}
__device__ __forceinline__ float wave_max_f(float v) {
#pragma unroll
  for (int o = 32; o > 0; o >>= 1) v = fmaxf(v, __shfl_xor(v, o));
  return v;
}
// async global->LDS, 16B per lane, wave-uniform LDS base (+lane*16 implicit)
__device__ __forceinline__ void gload16(const u16* g, u16* l) {
  __builtin_amdgcn_global_load_lds(
      (const __attribute__((address_space(1))) unsigned int*)g,
      (__attribute__((address_space(3))) unsigned int*)l,
      16, 0, 0);
}

// ---------- elementwise cast fp32 -> bf16 ----------
__global__ __launch_bounds__(256)
void cast_f32_bf16(const float* __restrict__ in, u16* __restrict__ out) {
  long i = ((long)blockIdx.x * 256 + threadIdx.x) * 4;
  f32x4 v = *(const f32x4*)(in + i);
  u16x4 o;
#pragma unroll
  for (int j = 0; j < 4; ++j) o[j] = f2bf(v[j]);
  *(u16x4*)(out + i) = o;
}

// ---------- concat 3 bias vectors (1024 each) ----------
__global__ __launch_bounds__(256)
void concat3(const float* __restrict__ a, const float* __restrict__ b,
             const float* __restrict__ c, float* __restrict__ o) {
  int i = blockIdx.x * 256 + threadIdx.x;
  o[i] = i < 1024 ? a[i] : (i < 2048 ? b[i - 1024] : c[i - 2048]);
}

// ---------- cast+transpose fp32 [R][C] -> bf16 [C][R] ----------
__global__ __launch_bounds__(256)
void transpose_cast_f32_bf16(const float* __restrict__ in, u16* __restrict__ out,
                             int R, int C) {
  __shared__ float tile[32][33];
  int r0 = blockIdx.y * 32, c0 = blockIdx.x * 32;
  int tid = threadIdx.x;
  int tr = tid >> 3, tc4 = (tid & 7) * 4;
  f32x4 v = *(const f32x4*)(in + (long)(r0 + tr) * C + c0 + tc4);
#pragma unroll
  for (int j = 0; j < 4; ++j) tile[tr][tc4 + j] = v[j];
  __syncthreads();
  u16x4 o;
#pragma unroll
  for (int j = 0; j < 4; ++j) o[j] = f2bf(tile[tc4 + j][tr]);
  *(u16x4*)(out + (long)(c0 + tr) * R + r0 + tc4) = o;
}

#define TBM 256
#define TBK 64

enum { EPI_BF16_BIAS = 0, EPI_BF16_SCALE = 1, EPI_BF16 = 2,
       EPI_RELU_BF16_BIAS = 3, EPI_BF16_BIAS_RESIDBF = 4, EPI_QKV_BIAS = 5 };

#define QUAD(MFA)                                                             \
  _Pragma("unroll")                                                           \
  for (int mf = (MFA); mf < (MFA) + 2; ++mf)                                  \
    _Pragma("unroll")                                                         \
    for (int nf = 0; nf < 4; ++nf) {                                          \
      acc[mf][nf] = __builtin_amdgcn_mfma_f32_16x16x32_bf16(                  \
          af[mf][0], bfr[nf][0], acc[mf][nf], 0, 0, 0);                       \
      acc[mf][nf] = __builtin_amdgcn_mfma_f32_16x16x32_bf16(                  \
          af[mf][1], bfr[nf][1], acc[mf][nf], 0, 0, 0);                       \
    }

__device__ __forceinline__ void epi_store(int EPIv, void* Cout, long cidx,
                                          float v, const float* bias, int col,
                                          const u16* resid, float scale) {
  if (EPIv == EPI_BF16_BIAS) {
    ((u16*)Cout)[cidx] = f2bf(v + bias[col]);
  } else if (EPIv == EPI_BF16_SCALE) {
    ((u16*)Cout)[cidx] = f2bf(v * scale);
  } else if (EPIv == EPI_BF16) {
    ((u16*)Cout)[cidx] = f2bf(v);
  } else if (EPIv == EPI_RELU_BF16_BIAS) {
    ((u16*)Cout)[cidx] = f2bf(fmaxf(v + bias[col], 0.0f));
  } else { // EPI_BF16_BIAS_RESIDBF
    ((u16*)Cout)[cidx] = f2bf(v + bias[col] + bf2f(resid[cidx]));
  }
}

// ---------- 8-wave 256x256 MFMA GEMM (R11-measured best for scores+FFN1) ----------
template <int EPI>
__global__ __launch_bounds__(512, 2)
void gemm8p(const u16* __restrict__ A, const u16* __restrict__ Bt,
            const float* __restrict__ bias, const u16* __restrict__ resid,
            void* __restrict__ Cout, int M, int N, int K, int lda, int ldb,
            int tx, int ty, long long batchA, long long batchB, long long batchC,
            float scale) {
  constexpr int BN_ = 256;
  constexpr int MF = 8;
  __shared__ u16 As[2][TBM * TBK];  // 2 x 32 KB
  __shared__ u16 Bs[2][BN_ * TBK];  // 2 x 32 KB

  // bijective XCD swizzle (m204)
  const int nwg = gridDim.x;
  const int orig = blockIdx.x;
  const int q = nwg >> 3, r = nwg & 7;
  const int xcd = orig & 7, idx = orig >> 3;
  const int wg = (xcd < r ? xcd * (q + 1) : r * (q + 1) + (xcd - r) * q) + idx;
  const int bx = wg % tx;
  const int tmp = wg / tx;
  const int by = tmp % ty;
  const int b  = tmp / ty;

  const u16* Ab = A + (long)b * batchA;
  const u16* Bb = Bt + (long)b * batchB;
  const int row0 = by * TBM;
  const int col0 = bx * BN_;
  const int tid = threadIdx.x;
  const int lane = tid & 63, wid = tid >> 6;     // 8 waves
  const int wm = wid >> 2, wn = wid & 3;         // 2M x 4N
  const int rowW = wm * 128;
  const int l15 = lane & 15, g = lane >> 4;

  const int sr = lane >> 3;
  const int sc = ((lane & 7) ^ sr) * 8;
  const int wrow = wid * 8 + sr;

  const int c0 = ((0 + g) ^ (l15 & 7)) * 8;
  const int c1 = ((4 + g) ^ (l15 & 7)) * 8;

  auto stageA = [&](int h, int kt, int bf_) {
#pragma unroll
    for (int j = 0; j < 2; ++j)
      gload16(Ab + (size_t)(row0 + h * 128 + j * 64 + wrow) * lda + kt * TBK + sc,
              &As[bf_][(h * 128 + j * 64 + wid * 8) * TBK]);
  };
  auto stageB = [&](int h, int kt, int bf_) {
#pragma unroll
    for (int j = 0; j < 2; ++j)
      gload16(Bb + (size_t)(col0 + h * 128 + j * 64 + wrow) * ldb + kt * TBK + sc,
              &Bs[bf_][(h * 128 + j * 64 + wid * 8) * TBK]);
  };

  s16x8 af[MF][2];
  s16x8 bfr[4][2];
  f32x4 acc[MF][4] = {};
  const int nt = K / TBK;

  stageA(0, 0, 0); stageA(1, 0, 0);
  stageB(0, 0, 0); stageB(1, 0, 0);
  if (nt > 1) {
    stageA(0, 1, 1); stageA(1, 1, 1);
    asm volatile("s_waitcnt vmcnt(4)" ::: "memory");
  } else {
    asm volatile("s_waitcnt vmcnt(0)" ::: "memory");
  }
  __builtin_amdgcn_s_barrier();

  for (int t = 0; t < nt; ++t) {
    const int cur = t & 1;
    const u16* Asc = &As[cur][0];
    const u16* Bsc = &Bs[cur][0];

    // ---- phase 0
#pragma unroll
    for (int nf = 0; nf < 4; ++nf) {
      const int rb = (wn * 64 + nf * 16 + l15) * TBK;
      bfr[nf][0] = *(const s16x8*)(Bsc + rb + c0);
      bfr[nf][1] = *(const s16x8*)(Bsc + rb + c1);
    }
#pragma unroll
    for (int mf = 0; mf < 4; ++mf) {
      const int rb = (rowW + mf * 16 + l15) * TBK;
      af[mf][0] = *(const s16x8*)(Asc + rb + c0);
      af[mf][1] = *(const s16x8*)(Asc + rb + c1);
    }
    if (t + 1 < nt) stageB(0, t + 1, cur ^ 1);
    __builtin_amdgcn_s_barrier();
    __builtin_amdgcn_s_setprio(1);
    QUAD(0)
    __builtin_amdgcn_s_setprio(0);
    __builtin_amdgcn_s_barrier();

    // ---- phase 1
#pragma unroll
    for (int mf = 4; mf < 8; ++mf) {
      const int rb = (rowW + mf * 16 + l15) * TBK;
      af[mf][0] = *(const s16x8*)(Asc + rb + c0);
      af[mf][1] = *(const s16x8*)(Asc + rb + c1);
    }
    if (t + 1 < nt) stageB(1, t + 1, cur ^ 1);
    __builtin_amdgcn_s_barrier();
    __builtin_amdgcn_s_setprio(1);
    QUAD(2)
    __builtin_amdgcn_s_setprio(0);
    asm volatile("s_waitcnt lgkmcnt(0)" ::: "memory");
    __builtin_amdgcn_sched_barrier(0);
    __builtin_amdgcn_s_barrier();

    // ---- phase 2
    if (t + 2 < nt) stageA(0, t + 2, cur);
    __builtin_amdgcn_s_barrier();
    __builtin_amdgcn_s_setprio(1);
    QUAD(4)
    __builtin_amdgcn_s_setprio(0);
    __builtin_amdgcn_s_barrier();

    // ---- phase 3
    if (t + 2 < nt) stageA(1, t + 2, cur);
    __builtin_amdgcn_s_barrier();
    __builtin_amdgcn_s_setprio(1);
    QUAD(6)
    __builtin_amdgcn_s_setprio(0);
    if (t + 1 < nt) {
      if (t + 2 < nt) asm volatile("s_waitcnt vmcnt(4)" ::: "memory");
      else            asm volatile("s_waitcnt vmcnt(0)" ::: "memory");
    }
    __builtin_amdgcn_s_barrier();
  }

  const long cb = (long)b * batchC;
#pragma unroll
  for (int mf = 0; mf < MF; ++mf) {
    const int rbase = row0 + rowW + mf * 16 + g * 4;
#pragma unroll
    for (int nf = 0; nf < 4; ++nf) {
      const int col = col0 + wn * 64 + nf * 16 + l15;
#pragma unroll
      for (int rr = 0; rr < 4; ++rr)
        epi_store(EPI, Cout, cb + (long)(rbase + rr) * N + col,
                  acc[mf][nf][rr], bias, col, resid, scale);
    }
  }
}

// ---------- 4-wave 128x128 MFMA GEMM: 2 blocks/CU, 2-phase counted-vmcnt ----------
// EPI_QKV_BIAS: N=3072 fused q|k|v projection; cols<2048 (q,k) stored normally
// to Cout, cols>=2048 (v) stored TRANSPOSED to vT[b][d][s] (passed via resid)
// as aligned u16x4 (4 consecutive s). Tile-uniform branch (2048 % 128 == 0).
template <int EPI>
__global__ __launch_bounds__(256, 2)
void gemm128(const u16* __restrict__ A, const u16* __restrict__ Bt,
             const float* __restrict__ bias, const u16* __restrict__ resid,
             void* __restrict__ Cout, int M, int N, int K, int lda, int ldb,
             int tx, int ty, long long batchA, long long batchB, long long batchC,
             float scale) {
  __shared__ u16 As[2][128 * TBK];  // 2 x 16 KB
  __shared__ u16 Bs[2][128 * TBK];  // 2 x 16 KB

  // bijective XCD swizzle (m204)
  const int nwg = gridDim.x;
  const int orig = blockIdx.x;
  const int q = nwg >> 3, r = nwg & 7;
  const int xcd = orig & 7, idx = orig >> 3;
  const int wg = (xcd < r ? xcd * (q + 1) : r * (q + 1) + (xcd - r) * q) + idx;
  const int bx = wg % tx;
  const int tmp = wg / tx;
  const int by = tmp % ty;
  const int b  = tmp / ty;

  const u16* Ab = A + (long)b * batchA;
  const u16* Bb = Bt + (long)b * batchB;
  const int row0 = by * 128;
  const int col0 = bx * 128;
  const int tid = threadIdx.x;
  const int lane = tid & 63, wid = tid >> 6;     // 4 waves
  const int wm = wid >> 1, wn = wid & 1;         // 2M x 2N
  const int rowW = wm * 64;
  const int l15 = lane & 15, g = lane >> 4;

  const int sr = lane >> 3;                  // row within 8-row slice
  const int sc = ((lane & 7) ^ sr) * 8;      // pre-swizzled source chunk
  const int wrow = wid * 8 + sr;             // 0..31

  const int c0 = ((0 + g) ^ (l15 & 7)) * 8;
  const int c1 = ((4 + g) ^ (l15 & 7)) * 8;

  auto stageA = [&](int h, int kt, int bf_) {  // half-tile = 64 rows, 2 issues
#pragma unroll
    for (int j = 0; j < 2; ++j)
      gload16(Ab + (size_t)(row0 + h * 64 + j * 32 + wrow) * lda + kt * TBK + sc,
              &As[bf_][(h * 64 + j * 32 + wid * 8) * TBK]);
  };
  auto stageB = [&](int h, int kt, int bf_) {
#pragma unroll
    for (int j = 0; j < 2; ++j)
      gload16(Bb + (size_t)(col0 + h * 64 + j * 32 + wrow) * ldb + kt * TBK + sc,
              &Bs[bf_][(h * 64 + j * 32 + wid * 8) * TBK]);
  };

  s16x8 af[4][2];
  s16x8 bfr[4][2];
  f32x4 acc[4][4] = {};
  const int nt = K / TBK;

  // prologue: tile0 (A+B) -> buf0, A(1) -> buf1; wait tile0's 8 issues
  stageA(0, 0, 0); stageA(1, 0, 0);
  stageB(0, 0, 0); stageB(1, 0, 0);
  if (nt > 1) {
    stageA(0, 1, 1); stageA(1, 1, 1);
    asm volatile("s_waitcnt vmcnt(4)" ::: "memory");
  } else {
    asm volatile("s_waitcnt vmcnt(0)" ::: "memory");
  }
  __builtin_amdgcn_s_barrier();

  for (int t = 0; t < nt; ++t) {
    const int cur = t & 1;
    const u16* Asc = &As[cur][0];
    const u16* Bsc = &Bs[cur][0];

    // ---- phase A: ALL frag reads; stage B(t+1) -> other buf
#pragma unroll
    for (int nf = 0; nf < 4; ++nf) {
      const int rb = (wn * 64 + nf * 16 + l15) * TBK;
      bfr[nf][0] = *(const s16x8*)(Bsc + rb + c0);
      bfr[nf][1] = *(const s16x8*)(Bsc + rb + c1);
    }
#pragma unroll
    for (int mf = 0; mf < 4; ++mf) {
      const int rb = (rowW + mf * 16 + l15) * TBK;
      af[mf][0] = *(const s16x8*)(Asc + rb + c0);
      af[mf][1] = *(const s16x8*)(Asc + rb + c1);
    }
    if (t + 1 < nt) { stageB(0, t + 1, cur ^ 1); stageB(1, t + 1, cur ^ 1); }
    // pin: my buf[cur] reads complete, then all-wave rendezvous
    asm volatile("s_waitcnt lgkmcnt(0)" ::: "memory");
    __builtin_amdgcn_sched_barrier(0);
    __builtin_amdgcn_s_barrier();
    __builtin_amdgcn_s_setprio(1);
    QUAD(0)
    __builtin_amdgcn_s_setprio(0);
    // ---- phase B: stage A(t+2) -> CURRENT buf; MFMA half 2
    if (t + 2 < nt) { stageA(0, t + 2, cur); stageA(1, t + 2, cur); }
    __builtin_amdgcn_s_setprio(1);
    QUAD(2)
    __builtin_amdgcn_s_setprio(0);
    if (t + 1 < nt) {
      if (t + 2 < nt) asm volatile("s_waitcnt vmcnt(4)" ::: "memory");
      else            asm volatile("s_waitcnt vmcnt(0)" ::: "memory");
      __builtin_amdgcn_s_barrier();
    }
  }

  const long cb = (long)b * batchC;
#pragma unroll
  for (int mf = 0; mf < 4; ++mf) {
    const int rbase = row0 + rowW + mf * 16 + g * 4;
#pragma unroll
    for (int nf = 0; nf < 4; ++nf) {
      const int col = col0 + wn * 64 + nf * 16 + l15;
      if constexpr (EPI == EPI_QKV_BIAS) {
        const float bs = bias[col];
        if (col < 2048) {               // q,k slice: normal row-major store
#pragma unroll
          for (int rr = 0; rr < 4; ++rr)
            ((u16*)Cout)[(long)(rbase + rr) * N + col] = f2bf(acc[mf][nf][rr] + bs);
        } else {                        // v slice: direct transposed store to vT
          const int row = rbase;        // rows rbase..rbase+3, same batch (S|128)
          const int bb = row >> 11;     // row / 2048
          const int s  = row & 2047;
          u16x4 o;
#pragma unroll
          for (int rr = 0; rr < 4; ++rr) o[rr] = f2bf(acc[mf][nf][rr] + bs);
          u16* vt = (u16*)resid;        // vT[b][d][s]
          *(u16x4*)(vt + ((long)bb * 1024 + (col - 2048)) * 2048 + s) = o;
        }
      } else {
#pragma unroll
        for (int rr = 0; rr < 4; ++rr)
          epi_store(EPI, Cout, cb + (long)(rbase + rr) * N + col,
                    acc[mf][nf][rr], bias, col, resid, scale);
      }
    }
  }
}

// ---------- per-row top-k threshold + sparse softmax: ONE WAVE PER ROW ----------
__global__ __launch_bounds__(256)
void topk_softmax(const u16* __restrict__ scores, u16* __restrict__ P, int topk) {
  const int lane = threadIdx.x & 63, wid = threadIdx.x >> 6;
  const long row = (long)blockIdx.x * 4 + wid;
  const long rowoff = row * 2048;

  float v[32]; uint32_t kv[32];
  const uint32_t* src = (const uint32_t*)(scores + rowoff);
#pragma unroll
  for (int j = 0; j < 16; ++j) {
    uint32_t w = src[j * 64 + lane];
    v[2 * j]     = bf2f((u16)(w & 0xFFFFu));
    v[2 * j + 1] = bf2f((u16)(w >> 16));
  }
#pragma unroll
  for (int j = 0; j < 32; ++j) {
    union { float f; uint32_t u; } c; c.f = v[j];
    kv[j] = (c.u & 0x80000000u) ? ~c.u : (c.u | 0x80000000u);  // monotonic key
  }
  float m = v[0];
#pragma unroll
  for (int j = 1; j < 32; ++j) m = fmaxf(m, v[j]);
  m = wave_max_f(m);

  uint32_t cur = 0;
  for (int bit = 31; bit >= 16; --bit) {   // 16-bit radix (exact for bf16 keys)
    const uint32_t cand = cur | (1u << bit);
    int c = 0;
#pragma unroll
    for (int j = 0; j < 32; ++j)
      c += (int)__popcll(__ballot(kv[j] >= cand));
    if (c >= topk) cur = cand;
  }

  const float mm = fmaxf(m, 0.0f);
  float p[32], s = 0.0f;
#pragma unroll
  for (int j = 0; j < 32; ++j) {
    float val = (kv[j] >= cur) ? v[j] : 0.0f;
    p[j] = __expf(val - mm);
    s += p[j];
  }
  s = wave_sum_f(s);
  const float inv = 1.0f / s;
  uint32_t* dst = (uint32_t*)(P + rowoff);
#pragma unroll
  for (int j = 0; j < 16; ++j) {
    uint32_t w = (uint32_t)f2bf(p[2 * j] * inv) |
                 ((uint32_t)f2bf(p[2 * j + 1] * inv) << 16);
    dst[j * 64 + lane] = w;
  }
}

// ---------- fused (a [+ bf16 r]) -> LayerNorm; a is fp32 OR bf16 ----------
__global__ __launch_bounds__(256)
void add_ln(const float* __restrict__ af, const u16* __restrict__ ab,
            const u16* __restrict__ r,
            const float* __restrict__ gamma, const float* __restrict__ beta,
            float* __restrict__ outf, u16* __restrict__ outb) {
  const long off = (long)blockIdx.x * 1024;
  const int tid = threadIdx.x, lane = tid & 63, wid = tid >> 6;
  const int c4 = tid * 4;
  __shared__ float sred[4];
  float x[4];
  if (af) {
    f32x4 av = *(const f32x4*)(af + off + c4);
#pragma unroll
    for (int j = 0; j < 4; ++j) x[j] = av[j];
  } else {
    u16x4 av = *(const u16x4*)(ab + off + c4);
#pragma unroll
    for (int j = 0; j < 4; ++j) x[j] = bf2f(av[j]);
  }
  if (r) {
    u16x4 rv = *(const u16x4*)(r + off + c4);
#pragma unroll
    for (int j = 0; j < 4; ++j) x[j] += bf2f(rv[j]);
  }
  float s = x[0] + x[1] + x[2] + x[3];
  s = wave_sum_f(s);
  if (lane == 0) sred[wid] = s;
  __syncthreads();
  float mu = (sred[0] + sred[1] + sred[2] + sred[3]) * (1.0f / 1024.0f);
  __syncthreads();
  float qv = 0.0f;
#pragma unroll
  for (int j = 0; j < 4; ++j) { float d = x[j] - mu; qv += d * d; }
  qv = wave_sum_f(qv);
  if (lane == 0) sred[wid] = qv;
  __syncthreads();
  float var = (sred[0] + sred[1] + sred[2] + sred[3]) * (1.0f / 1024.0f);
  float inv = rsqrtf(var + 1e-6f);
  f32x4 gv = *(const f32x4*)(gamma + c4);
  f32x4 bv = *(const f32x4*)(beta + c4);
  f32x4 ov; u16x4 ob;
#pragma unroll
  for (int j = 0; j < 4; ++j) {
    float o = (x[j] - mu) * inv * gv[j] + bv[j];
    ov[j] = o; ob[j] = f2bf(o);
  }
  if (outf) *(f32x4*)(outf + off + c4) = ov;
  if (outb) *(u16x4*)(outb + off + c4) = ob;
}

// ---------- launch ----------
extern "C" void kernel_launch(void* const* d_in, const int* in_sizes, int n_in,
                              void* d_out, int out_size, void* d_ws, size_t ws_size,
                              hipStream_t stream) {
  const float* x   = (const float*)d_in[0];
  const float* Wq  = (const float*)d_in[1];
  const float* bq  = (const float*)d_in[2];
  const float* Wk  = (const float*)d_in[3];
  const float* bk  = (const float*)d_in[4];
  const float* Wv  = (const float*)d_in[5];
  const float* bv  = (const float*)d_in[6];
  const float* W1  = (const float*)d_in[7];
  const float* b1  = (const float*)d_in[8];
  const float* W2  = (const float*)d_in[9];
  const float* b2  = (const float*)d_in[10];
  const float* g1  = (const float*)d_in[11];
  const float* be1 = (const float*)d_in[12];
  const float* g2  = (const float*)d_in[13];
  const float* be2 = (const float*)d_in[14];

  const int Bz = 4, S = 2048, Dm = 1024, Ff = 4096;
  const int M = Bz * S; // 8192
  const int N3 = 3 * Dm; // 3072

  char* ws = (char*)d_ws;
  const size_t MBy = 1024u * 1024u;
  u16*  wqkvT  = (u16*)(ws + 0 * MBy);     // 6 MB  [3072][1024]
  u16*  w1T    = (u16*)(ws + 6 * MBy);     // 8 MB  [Ff][Dm]
  u16*  w2T    = (u16*)(ws + 14 * MBy);    // 8 MB  [Dm][Ff]
  u16*  xbf    = (u16*)(ws + 23 * MBy);    // 16 MB (live through LN1)
  u16*  qkv    = (u16*)(ws + 39 * MBy);    // 48 MB [8192][3072] q|k (v cols unused)
  u16*  vT     = (u16*)(ws + 87 * MBy);    // 16 MB [B][Dm][S] written by QKV epi
  float* bqkv  = (float*)(ws + 103 * MBy); // 12 KB (live only during QKV GEMM)
  u16*  scores = (u16*)(ws + 103 * MBy);   // 32 MB [B][S][S] bf16 (after QKV done)
  u16*  P      = (u16*)(ws + 167 * MBy);   // 32 MB
  u16*  attn   = (u16*)(ws + 135 * MBy);   // 16 MB bf16
  u16*  out1b  = (u16*)(ws + 151 * MBy);   // 16 MB (own slab; xbf stays live)
  u16*  y      = (u16*)(ws + 167 * MBy);   // 16 MB bf16 (reuse P; P dead after PV)

  dim3 blk(256);
  dim3 blk8(512);

  // casts / weight prep (plain-pointer launches; no H2D copies)
  cast_f32_bf16<<<dim3((unsigned)((long)M * Dm / 1024)), blk, 0, stream>>>(x, xbf);
  transpose_cast_f32_bf16<<<dim3(Dm / 32, Dm / 32), blk, 0, stream>>>(Wq, wqkvT, Dm, Dm);
  transpose_cast_f32_bf16<<<dim3(Dm / 32, Dm / 32), blk, 0, stream>>>(Wk, wqkvT + 1024 * 1024, Dm, Dm);
  transpose_cast_f32_bf16<<<dim3(Dm / 32, Dm / 32), blk, 0, stream>>>(Wv, wqkvT + 2048 * 1024, Dm, Dm);
  transpose_cast_f32_bf16<<<dim3(Ff / 32, Dm / 32), blk, 0, stream>>>(W1, w1T, Dm, Ff);
  transpose_cast_f32_bf16<<<dim3(Dm / 32, Ff / 32), blk, 0, stream>>>(W2, w2T, Ff, Dm);
  concat3<<<dim3(12), blk, 0, stream>>>(bq, bk, bv, bqkv);

  // fused QKV projection: q,k -> qkv rows; v -> vT transposed directly
  gemm128<EPI_QKV_BIAS><<<dim3(24 * 64), blk, 0, stream>>>(
      xbf, wqkvT, bqkv, (const u16*)vT, qkv, M, N3, Dm, Dm, Dm, 24, 64, 0, 0, 0, 1.0f);

  // scores[b] = q[b] @ k[b]^T / sqrt(Dm) -> bf16   (256^2: 8x8x4=256 blocks)
  gemm8p<EPI_BF16_SCALE><<<dim3(8 * 8 * Bz), blk8, 0, stream>>>(
      qkv, qkv + 1024, nullptr, nullptr, scores, S, S, Dm, N3, N3, 8, 8,
      (long long)S * N3, (long long)S * N3, (long long)S * S, 0.03125f);

  // top-k threshold + sparse softmax -> P (bf16): one wave per row
  topk_softmax<<<dim3(Bz * S / 4), blk, 0, stream>>>(scores, P, S / 2);

  // attn_out[b] = P[b] @ v[b] -> bf16   (128^2: 8x16x4=512 blocks)
  gemm128<EPI_BF16><<<dim3(8 * 16 * Bz), blk, 0, stream>>>(
      P, vT, nullptr, nullptr, attn, S, Dm, S, S, S, 8, 16,
      (long long)S * S, (long long)Dm * S, (long long)S * Dm, 1.0f);

  // out1 = LN(xbf + attn_out) -> bf16 only (both inputs bf16)
  add_ln<<<dim3(M), blk, 0, stream>>>(nullptr, xbf, attn, g1, be1, nullptr, out1b);

  // h = relu(out1 @ W1 + b1) -> bf16   (256^2: 16x32=512 blocks)
  gemm8p<EPI_RELU_BF16_BIAS><<<dim3(16 * 32), blk8, 0, stream>>>(
      out1b, w1T, b1, nullptr, qkv /*hbf reuse*/, M, Ff, Dm, Dm, Dm, 16, 32, 0, 0, 0, 1.0f);

  // y = h @ W2 + b2 + out1 (bf16 resid) -> bf16   (128^2: 8x64=512 blocks)
  gemm128<EPI_BF16_BIAS_RESIDBF><<<dim3(8 * 64), blk, 0, stream>>>(
      qkv /*hbf*/, w2T, b2, out1b, y, M, Dm, Ff, Ff, Ff, 8, 64, 0, 0, 0, 1.0f);

  // out = LN(y)  (y bf16)
  add_ln<<<dim3(M), blk, 0, stream>>>(nullptr, y, nullptr, g2, be2, (float*)d_out, nullptr);
}